// Round 9
// baseline (181.151 us; speedup 1.0000x reference)
//
#include <hip/hip_runtime.h>
#include <hip/hip_bf16.h>
#include <math.h>

// HMM forward (logZ), K=64 tags, V=50000, D=128, BATCH=8192, L=126.
// r16 (resubmit; r8 bench hit GPUAcquisitionTimeout — no signal):
// sync-free 2-kernel pipeline. Evidence so far:
//   r12 (3 kernels, no sync):        128.0 us   <- best
//   r14 (1 kernel, 2 grid barriers): 189.6 us (kernel alone 126.5)
//   r15 (2 kernels, atomic sumexp):  145.4 us
// => device-scope sync is poison on 8-XCD gfx950: grid barriers cost
// ~40-60us (per-barrier cross-XCD L2 wb/inv + 511 spinning blocks);
// 50K device-scope f32 atomicAdds onto 64 floats cost ~15us (4 lines
// ping-ponging across XCDs). Kernel boundaries (~5us) are the cheapest
// release/acquire available. r16 = r12 structure minus the k_sumA
// dispatch, minus all atomics:
//   k_emit: verified r12 emit; column sums -> partial[tile][k]
//     (TRANSPOSED: one coalesced 256B store per block, no atomics).
//   k_scan: each block redundantly reduces partial (4 waves x 196
//     coalesced 256B rows, L2-resident, ~1-2us) into LDS sumexp, and
//     computes A = softmax(WA)+EPS per block (r15 code); then the
//     verified producer/consumer scan. No memset node.
//
// fp8 row layout: tag k = 32*h + 8*qA + j  ->  byte 16*qA + 8*h + j.
//
// ws layout:
//   [0, 3,200,000)        btn8[v][64]     fp8e4m3  exp(logit), permuted order
//   [3,200,000, +200192)  partial[782][64] f32     per-tile column sums

#define KT 64
#define VV 50000
#define DD 128
#define BOS_T 62
#define EOS_T 63
#define LLEN 126
#define EPSF 1e-45f
#define SCALE_F 65536.0f
#define LOG_TOTAL_SCALE (2016.0f * 0.6931471805599453f)
#define NBLK 782          // emit tiles (1 per block)
#define TPH 21            // fwd steps per phase (126 = 6*21)
#define NPH 6
#define GRIDN 512         // scan grid: 8192/16 sentences per block

#define BTN_OFF   0
#define PART_OFF  3200000

typedef short short8 __attribute__((ext_vector_type(8)));
typedef float f32x4  __attribute__((ext_vector_type(4)));
typedef float f32x2  __attribute__((ext_vector_type(2)));

union U8 { short8 v; unsigned u[4]; short s[8]; };

static __device__ inline unsigned short f2bf_u(float x) {
    __hip_bfloat16 h = __float2bfloat16(x);
    return *reinterpret_cast<unsigned short*>(&h);
}
static __device__ inline short f2bf(float x) { return (short)f2bf_u(x); }

#if __has_builtin(__builtin_amdgcn_cvt_pk_bf16_f32)
typedef __bf16 bf16x2 __attribute__((ext_vector_type(2)));
static __device__ inline unsigned pk2(float a, float b) {
    bf16x2 r = __builtin_amdgcn_cvt_pk_bf16_f32(a, b);
    return *reinterpret_cast<unsigned*>(&r);
}
#else
static __device__ inline unsigned pk2(float a, float b) {
    union { float f; unsigned u; } ua, ub;
    ua.f = a; ub.f = b;
    return ((ua.u + 0x8000u) >> 16) | ((ub.u + 0x8000u) & 0xFFFF0000u);
}
#endif

// ---- fp8 e4m3fn pack/unpack (values here are positive normals in [0.7,1.5])
#if __has_builtin(__builtin_amdgcn_cvt_pk_fp8_f32)
static __device__ inline unsigned pk4f8(float a, float b, float c, float d) {
    int v = __builtin_amdgcn_cvt_pk_fp8_f32(a, b, 0, false);
    v = __builtin_amdgcn_cvt_pk_fp8_f32(c, d, v, true);
    return (unsigned)v;
}
#else
static __device__ inline unsigned enc1f8(float x) {
    union { float f; unsigned u; } c; c.f = x;
    unsigned u = c.u & 0x7FFFFFFFu;
    unsigned r = u + 0x7FFFFu + ((u >> 20) & 1u);   // RNE to 3 mantissa bits
    return ((r >> 20) - (120u << 3)) & 0x7Fu;       // rebias 127->7
}
static __device__ inline unsigned pk4f8(float a, float b, float c, float d) {
    return enc1f8(a) | (enc1f8(b) << 8) | (enc1f8(c) << 16) | (enc1f8(d) << 24);
}
#endif

#if __has_builtin(__builtin_amdgcn_cvt_pk_f32_fp8)
static __device__ inline f32x2 dec2lo(unsigned w) { return __builtin_amdgcn_cvt_pk_f32_fp8((int)w, false); }
static __device__ inline f32x2 dec2hi(unsigned w) { return __builtin_amdgcn_cvt_pk_f32_fp8((int)w, true); }
#else
static __device__ inline float dec1f8(unsigned b) {
    union { unsigned u; float f; } c;
    c.u = ((b & 0x80u) << 24) | (((b & 0x7Fu) << 20) + (120u << 23));
    return c.f;
}
static __device__ inline f32x2 dec2lo(unsigned w) { f32x2 r; r.x = dec1f8(w & 0xFF); r.y = dec1f8((w >> 8) & 0xFF); return r; }
static __device__ inline f32x2 dec2hi(unsigned w) { f32x2 r; r.x = dec1f8((w >> 16) & 0xFF); r.y = dec1f8(w >> 24); return r; }
#endif

// async global(per-lane addr) -> LDS(uniform base + lane*16B), 16 B/lane
#if __has_builtin(__builtin_amdgcn_global_load_lds)
#define GLLDS(gp, lbase)                                                        \
    __builtin_amdgcn_global_load_lds(                                           \
        (__attribute__((address_space(1))) void*)const_cast<unsigned char*>(gp),\
        (__attribute__((address_space(3))) void*)(lbase), 16, 0, 0)
#else
#define GLLDS(gp, lbase)                                                        \
    do { *(uint4*)((unsigned char*)(lbase) + (threadIdx.x & 63) * 16) =         \
             *(const uint4*)(gp); } while (0)
#endif

// ---------------------------------------------------------------- btn8[v][pos(k)] = fp8(exp(ThetaB[k].E[v]))  (MFMA GEMM)
__global__ __launch_bounds__(256) void k_emit(const float* __restrict__ ThetaB,
                                              const float* __restrict__ E,
                                              unsigned char* __restrict__ btn8,
                                              float* __restrict__ partial) {
    __shared__ float red[4][KT];
    int t    = threadIdx.x;
    int lane = t & 63;
    int w    = t >> 6;
    int n    = lane & 15;
    int q    = lane >> 4;
    int v0   = (blockIdx.x * 4 + w) * 16;

    // B-frags from E rows (cold HBM traffic — issue early): B[k=q*8+j][n=v]
    int rowE = v0 + n;
    bool valid = rowE < VV;
    rowE = valid ? rowE : VV - 1;
    float4 ex[4][2];
#pragma unroll
    for (int kt = 0; kt < 4; ++kt) {
        const float* p = E + (size_t)rowE * DD + kt * 32 + q * 8;
        ex[kt][0] = *(const float4*)p;
        ex[kt][1] = *(const float4*)(p + 4);
    }

    // A-frags from ThetaB: A[m=tag][k]: lane m=lane&15, k=q*8+j
    short8 Th[4][4];
#pragma unroll
    for (int kt = 0; kt < 4; ++kt)
#pragma unroll
        for (int mt = 0; mt < 4; ++mt) {
            const float* p = ThetaB + (mt * 16 + n) * DD + kt * 32 + q * 8;
            float4 x = *(const float4*)p;
            float4 y = *(const float4*)(p + 4);
            U8 f;
            f.u[0] = pk2(x.x, x.y); f.u[1] = pk2(x.z, x.w);
            f.u[2] = pk2(y.x, y.y); f.u[3] = pk2(y.z, y.w);
            Th[kt][mt] = f.v;
        }

    short8 Ef[4];
#pragma unroll
    for (int kt = 0; kt < 4; ++kt) {
        U8 f;
        f.u[0] = pk2(ex[kt][0].x, ex[kt][0].y); f.u[1] = pk2(ex[kt][0].z, ex[kt][0].w);
        f.u[2] = pk2(ex[kt][1].x, ex[kt][1].y); f.u[3] = pk2(ex[kt][1].z, ex[kt][1].w);
        Ef[kt] = f.v;
    }

#pragma unroll
    for (int mt = 0; mt < 4; ++mt) {
        f32x4 C = {0.f, 0.f, 0.f, 0.f};
#pragma unroll
        for (int kt = 0; kt < 4; ++kt)
            C = __builtin_amdgcn_mfma_f32_16x16x32_bf16(Th[kt][mt], Ef[kt], C, 0, 0, 0);
        // C[r]: tag tt = mt*16 + q*4 + r, v-col = n
        float e[4];
#pragma unroll
        for (int r = 0; r < 4; ++r) e[r] = __expf(C[r]);
        if (valid) {
            // permuted byte position of tag tt = 32h + 8qA + j: 16*qA + 8*h + j
            // for tt = mt*16 + q*4 + r: qA=(2mt+(q>>1))&3, h=mt>>1, j=(q&1)*4+r
            int pos = 16 * ((2 * mt + (q >> 1)) & 3) + 8 * (mt >> 1) + (q & 1) * 4;
            *(unsigned*)(btn8 + (size_t)rowE * KT + pos) = pk4f8(e[0], e[1], e[2], e[3]);
        }
        // column sums: reduce over the 16 v-lanes (lane bits 0-3)
#pragma unroll
        for (int r = 0; r < 4; ++r) {
            float s = valid ? e[r] : 0.0f;
            s += __shfl_xor(s, 1, 64);
            s += __shfl_xor(s, 2, 64);
            s += __shfl_xor(s, 4, 64);
            s += __shfl_xor(s, 8, 64);
            if (n == 0) red[w][mt * 16 + q * 4 + r] = s;
        }
    }
    __syncthreads();
    if (w == 0) {
        float s = red[0][lane] + red[1][lane] + red[2][lane] + red[3][lane];
        partial[blockIdx.x * KT + lane] = s;   // transposed: coalesced 256B
    }
}

// ---------------------------------------------------------------- forward scan
// 4 waves/block: waves 0-2 producers, wave 3 consumer; 16 sentences/block.
// Prologue per block: reduce partial[782][64] -> sumexp LDS (coalesced,
// L2-resident) and A = softmax(WA)+EPS into LDS. No atomics, no barriers.
__global__ __launch_bounds__(256) void k_scan(const int* __restrict__ words,
                                              const float* __restrict__ WA,
                                              const unsigned char* __restrict__ btn8,
                                              const float* __restrict__ partial,
                                              float* __restrict__ out) {
    __shared__ float A_lds[KT][KT];                                           // 16384 B
    __shared__ float sred[4][KT];                                             // 1024 B
    __shared__ float sum_lds[KT];                                             // 256 B
    __shared__ int shw[16 * LLEN];                                            // 8064 B
    __shared__ __attribute__((aligned(16))) unsigned char shE[2][TPH * 1024]; // 43008 B
    int lane = threadIdx.x & 63;
    int w    = threadIdx.x >> 6;   // waves 0-2: producers, wave 3: consumer
    int n    = lane & 15;          // sentence col (B/C side); row m (A side)
    int qA   = lane >> 4;
    int b0   = blockIdx.x * 16;

    // Stage word indices (contiguous 8064 B) cooperatively.
    {
        const uint4* src = (const uint4*)(words + (size_t)b0 * LLEN);
        uint4* dst = (uint4*)shw;
        for (int idx = threadIdx.x; idx < (16 * LLEN) / 4; idx += 256)
            dst[idx] = src[idx];
    }

    // sumexp: wave w reduces tiles [w*196, min(w*196+196, 782)), lane = tag.
    // partial is tile-major -> each iteration is a coalesced 256B row.
    {
        float s = 0.0f;
        int beg = w * 196;
        int end = beg + 196 < NBLK ? beg + 196 : NBLK;
        for (int i = beg; i < end; ++i) s += partial[i * KT + lane];
        sred[w][lane] = s;
    }

    // A rows: wave w computes rows w*16..w*16+15; lane = column entry.
    for (int rr = 0; rr < 16; ++rr) {
        int row = w * 16 + rr;
        float wv = WA[row * KT + lane];
        float e = (lane == BOS_T) ? 0.0f : __expf(wv);
        float se = e;
#pragma unroll
        for (int off = 32; off > 0; off >>= 1) se += __shfl_xor(se, off, 64);
        A_lds[row][lane] = e / se + EPSF;
    }
    __syncthreads();   // shw + A_lds + sred staged
    if (threadIdx.x < KT)
        sum_lds[threadIdx.x] = sred[0][threadIdx.x] + sred[1][threadIdx.x] +
                               sred[2][threadIdx.x] + sred[3][threadIdx.x];
    __syncthreads();

    // Consumer-only state
    short8 Af[2][4];
    short8 B0, B1;
    if (w == 3) {
        // A-operand frags of scaled T'^T; tag at C-position (mt, m):
        //   tagn = 32*(mt>>1) + 8*(m>>2) + 4*(mt&1) + (m&3)
#pragma unroll
        for (int mt = 0; mt < 4; ++mt) {
            int tagn = 32 * (mt >> 1) + 8 * (n >> 2) + 4 * (mt & 1) + (n & 3);
            float s = sum_lds[tagn];
            float rsn = (tagn == BOS_T || tagn == EOS_T) ? 0.0f : (SCALE_F / s);
#pragma unroll
            for (int kt = 0; kt < 2; ++kt) {
                U8 f;
#pragma unroll
                for (int j = 0; j < 8; ++j)
                    f.s[j] = f2bf(A_lds[kt * 32 + qA * 8 + j][tagn] * rsn);
                Af[kt][mt] = f.v;
            }
        }
        // beta_0 one-hot at tag 62 = B-position (kt=1, q=3, j=6)
        U8 z; z.u[0] = z.u[1] = z.u[2] = z.u[3] = 0;
        B0 = z.v;
        U8 o; o.u[0] = o.u[1] = o.u[2] = o.u[3] = 0;
        if (qA == 3) o.s[6] = (short)0x3F80;   // bf16(1.0)
        B1 = o.v;
    }

    // producer staging of phase p_ into buffer bb: wave w takes steps w, w+3, ...
    // one GLLDS per step: 64 lanes x 16B = 16 sentences' permuted fp8 rows
#define PSTAGE(bb, p_)                                                        \
    do {                                                                      \
        for (int s_ = w; s_ < TPH; s_ += 3) {                                 \
            int wd_ = shw[n * LLEN + (p_) * TPH + s_];                        \
            const unsigned char* g_ = btn8 + (size_t)wd_ * KT + qA * 16;      \
            GLLDS(g_, &shE[bb][s_ * 1024]);                                   \
        }                                                                     \
        asm volatile("s_waitcnt vmcnt(0)" ::: "memory");                      \
    } while (0)

#define LDE(bb, ss) (*(const uint4*)(&shE[bb][(ss) * 1024] + lane * 16))

    if (w < 3) PSTAGE(0, 0);
    __syncthreads();   // phase 0 ready

    for (int p = 0; p < NPH; ++p) {
        int b = p & 1;
        if (w < 3) {
            if (p + 1 < NPH) PSTAGE((p + 1) & 1, p + 1);
        } else {
            // consumer: TPH steps from buffer b, no VMEM
            uint4 r0 = LDE(b, 0);
            uint4 r1 = LDE(b, 1);
#pragma unroll
            for (int s = 0; s < TPH; ++s) {
                uint4 rc = r0;
                r0 = r1;
                int s2 = (s + 2 < TPH) ? s + 2 : TPH - 1;
                r1 = LDE(b, s2);

                // decode 16 fp8 (prefetched 2 steps ago -> off the chain)
                f32x2 d0 = dec2lo(rc.x), d1 = dec2hi(rc.x);
                f32x2 d2 = dec2lo(rc.y), d3 = dec2hi(rc.y);
                f32x2 d4 = dec2lo(rc.z), d5 = dec2hi(rc.z);
                f32x2 d6 = dec2lo(rc.w), d7 = dec2hi(rc.w);

                // C[mt] = Af[0][mt] x B0 + Af[1][mt] x B1
                f32x4 C[4];
#pragma unroll
                for (int mt = 0; mt < 4; ++mt) {
                    f32x4 acc = {0.f, 0.f, 0.f, 0.f};
                    acc = __builtin_amdgcn_mfma_f32_16x16x32_bf16(Af[0][mt], B0, acc, 0, 0, 0);
                    acc = __builtin_amdgcn_mfma_f32_16x16x32_bf16(Af[1][mt], B1, acc, 0, 0, 0);
                    C[mt] = acc;
                }
                // next B-frags: kt slot j <- C[2kt+(j>>2)][j&3] * e_j  (in-lane)
                U8 f0, f1;
                f0.u[0] = pk2(C[0][0] * d0.x, C[0][1] * d0.y);
                f0.u[1] = pk2(C[0][2] * d1.x, C[0][3] * d1.y);
                f0.u[2] = pk2(C[1][0] * d2.x, C[1][1] * d2.y);
                f0.u[3] = pk2(C[1][2] * d3.x, C[1][3] * d3.y);
                f1.u[0] = pk2(C[2][0] * d4.x, C[2][1] * d4.y);
                f1.u[1] = pk2(C[2][2] * d5.x, C[2][3] * d5.y);
                f1.u[2] = pk2(C[3][0] * d6.x, C[3][1] * d6.y);
                f1.u[3] = pk2(C[3][2] * d7.x, C[3][3] * d7.y);
                B0 = f0.v; B1 = f1.v;
            }
        }
        __syncthreads();   // producers drained next phase; consumer done with b
    }

    // logZ = log(sum_k beta[k][n] * A[k][EOS]) - total scale
    if (w == 3) {
        short8 Afin[2];
#pragma unroll
        for (int kt = 0; kt < 2; ++kt) {
            U8 f;
#pragma unroll
            for (int j = 0; j < 8; ++j)
                f.s[j] = (n == 0) ? f2bf(A_lds[kt * 32 + qA * 8 + j][EOS_T]) : (short)0;
            Afin[kt] = f.v;
        }
        f32x4 Cf = {0.f, 0.f, 0.f, 0.f};
        Cf = __builtin_amdgcn_mfma_f32_16x16x32_bf16(Afin[0], B0, Cf, 0, 0, 0);
        Cf = __builtin_amdgcn_mfma_f32_16x16x32_bf16(Afin[1], B1, Cf, 0, 0, 0);
        if (qA == 0)
            out[b0 + n] = logf(Cf[0]) - LOG_TOTAL_SCALE;
    }
#undef PSTAGE
#undef LDE
}

extern "C" void kernel_launch(void* const* d_in, const int* in_sizes, int n_in,
                              void* d_out, int out_size, void* d_ws, size_t ws_size,
                              hipStream_t stream) {
    const int*   words  = (const int*)d_in[0];     // [8192,126]
    const float* ThetaB = (const float*)d_in[1];   // [64,128]
    const float* WA     = (const float*)d_in[2];   // [64,64]
    const float* E      = (const float*)d_in[3];   // [50000,128]
    float* out = (float*)d_out;                    // [8192]

    char* ws = (char*)d_ws;
    unsigned char* btn8 = (unsigned char*)(ws + BTN_OFF);
    float* partial = (float*)(ws + PART_OFF);

    k_emit<<<NBLK, 256, 0, stream>>>(ThetaB, E, btn8, partial);
    k_scan<<<GRIDN, 256, 0, stream>>>(words, WA, btn8, partial, out);
}

// Round 11
// 130.024 us; speedup vs baseline: 1.3932x; 1.3932x over previous
//
#include <hip/hip_runtime.h>
#include <hip/hip_bf16.h>
#include <math.h>

// HMM forward (logZ), K=64 tags, V=50000, D=128, BATCH=8192, L=126.
// r17 (resubmit; r10 bench hit GPUAcquisitionTimeout — no signal):
// barrier-free deep-prefetch scan. Measured attribution (r16):
//   fill (harness ws poison, fixed)  ~44 us
//   k_emit                           ~10 us (invisible, <44)
//   k_scan (r16, 2 prologues)        118 us  <- measured, top-5
//   r12's scan (no prologues)        ~54 us  (inferred)
// Prologue lesson: per-block redundant reductions are serial-latency chains
// (196-iter partial reduce ~= +43us, A-softmax ~= +21us) with nothing to
// hide them at 2 blocks/CU. Even r12's scan is latency-structure-bound
// (all pipes <12% busy): 1 consumer wave serialized against producer
// vmcnt(0) drains + 6 phase barriers.
// r17 scan redesign: 512 blocks x 64 threads, one INDEPENDENT wave per
// block, 16 sentences each. No producers, no barriers, no vmcnt(0).
// Per-lane direct 16B gathers into a 9-deep statically-indexed register
// pipeline (9 | 126; all pf[]/wdn[] indices compile-time -> no scratch);
// word indices prefetched from LDS 18 steps ahead. Gather latency (~600cy
// L3) hides under 9 steps x ~100cy chain. Consumer math verbatim r12.
// k_emit + k_sumA: verbatim r12 (verified, ~14us combined).
//
// fp8 row layout: tag k = 32*h + 8*qA + j  ->  byte 16*qA + 8*h + j.
//
// ws layout (r12):
//   [0, 3,200,000)        btn8[v][64]   fp8e4m3  raw exp(logit), permuted order
//   [3,200,000, +16384)   A[i][j]       f32      softmax(WA, col BOS=-inf)+EPS
//   [3,216,384, +256)     sumexp[k]     f32
//   [3,216,640, +200704)  partial[k][784] f32    per-block column sums

#define KT 64
#define VV 50000
#define DD 128
#define BOS_T 62
#define EOS_T 63
#define LLEN 126
#define EPSF 1e-45f
#define SCALE_F 65536.0f
#define LOG_TOTAL_SCALE (2016.0f * 0.6931471805599453f)
#define NBLK 782          // k_emit grid
#define PBLK 784          // padded partial row
#define PFD 9             // prefetch depth (divides 126)
#define ROUNDS (LLEN / PFD)

#define BTN_OFF   0
#define A_OFF     3200000
#define SUM_OFF   3216384
#define PART_OFF  3216640

typedef short short8 __attribute__((ext_vector_type(8)));
typedef float f32x4  __attribute__((ext_vector_type(4)));
typedef float f32x2  __attribute__((ext_vector_type(2)));

union U8 { short8 v; unsigned u[4]; short s[8]; };

static __device__ inline unsigned short f2bf_u(float x) {
    __hip_bfloat16 h = __float2bfloat16(x);
    return *reinterpret_cast<unsigned short*>(&h);
}
static __device__ inline short f2bf(float x) { return (short)f2bf_u(x); }

#if __has_builtin(__builtin_amdgcn_cvt_pk_bf16_f32)
typedef __bf16 bf16x2 __attribute__((ext_vector_type(2)));
static __device__ inline unsigned pk2(float a, float b) {
    bf16x2 r = __builtin_amdgcn_cvt_pk_bf16_f32(a, b);
    return *reinterpret_cast<unsigned*>(&r);
}
#else
static __device__ inline unsigned pk2(float a, float b) {
    union { float f; unsigned u; } ua, ub;
    ua.f = a; ub.f = b;
    return ((ua.u + 0x8000u) >> 16) | ((ub.u + 0x8000u) & 0xFFFF0000u);
}
#endif

// ---- fp8 e4m3fn pack/unpack (values here are positive normals in [0.7,1.5])
#if __has_builtin(__builtin_amdgcn_cvt_pk_fp8_f32)
static __device__ inline unsigned pk4f8(float a, float b, float c, float d) {
    int v = __builtin_amdgcn_cvt_pk_fp8_f32(a, b, 0, false);
    v = __builtin_amdgcn_cvt_pk_fp8_f32(c, d, v, true);
    return (unsigned)v;
}
#else
static __device__ inline unsigned enc1f8(float x) {
    union { float f; unsigned u; } c; c.f = x;
    unsigned u = c.u & 0x7FFFFFFFu;
    unsigned r = u + 0x7FFFFu + ((u >> 20) & 1u);   // RNE to 3 mantissa bits
    return ((r >> 20) - (120u << 3)) & 0x7Fu;       // rebias 127->7
}
static __device__ inline unsigned pk4f8(float a, float b, float c, float d) {
    return enc1f8(a) | (enc1f8(b) << 8) | (enc1f8(c) << 16) | (enc1f8(d) << 24);
}
#endif

#if __has_builtin(__builtin_amdgcn_cvt_pk_f32_fp8)
static __device__ inline f32x2 dec2lo(unsigned w) { return __builtin_amdgcn_cvt_pk_f32_fp8((int)w, false); }
static __device__ inline f32x2 dec2hi(unsigned w) { return __builtin_amdgcn_cvt_pk_f32_fp8((int)w, true); }
#else
static __device__ inline float dec1f8(unsigned b) {
    union { unsigned u; float f; } c;
    c.u = ((b & 0x80u) << 24) | (((b & 0x7Fu) << 20) + (120u << 23));
    return c.f;
}
static __device__ inline f32x2 dec2lo(unsigned w) { f32x2 r; r.x = dec1f8(w & 0xFF); r.y = dec1f8((w >> 8) & 0xFF); return r; }
static __device__ inline f32x2 dec2hi(unsigned w) { f32x2 r; r.x = dec1f8((w >> 16) & 0xFF); r.y = dec1f8(w >> 24); return r; }
#endif

// ---------------------------------------------------------------- btn8[v][pos(k)] = fp8(exp(ThetaB[k].E[v]))  (MFMA GEMM)
__global__ __launch_bounds__(256) void k_emit(const float* __restrict__ ThetaB,
                                              const float* __restrict__ E,
                                              unsigned char* __restrict__ btn8,
                                              float* __restrict__ partial) {
    __shared__ float red[4][KT];
    int t    = threadIdx.x;
    int lane = t & 63;
    int w    = t >> 6;
    int n    = lane & 15;
    int q    = lane >> 4;
    int v0   = (blockIdx.x * 4 + w) * 16;

    // B-frags from E rows (cold HBM traffic — issue early): B[k=q*8+j][n=v]
    int rowE = v0 + n;
    bool valid = rowE < VV;
    rowE = valid ? rowE : VV - 1;
    float4 ex[4][2];
#pragma unroll
    for (int kt = 0; kt < 4; ++kt) {
        const float* p = E + (size_t)rowE * DD + kt * 32 + q * 8;
        ex[kt][0] = *(const float4*)p;
        ex[kt][1] = *(const float4*)(p + 4);
    }

    // A-frags from ThetaB: A[m=tag][k]: lane m=lane&15, k=q*8+j
    short8 Th[4][4];
#pragma unroll
    for (int kt = 0; kt < 4; ++kt)
#pragma unroll
        for (int mt = 0; mt < 4; ++mt) {
            const float* p = ThetaB + (mt * 16 + n) * DD + kt * 32 + q * 8;
            float4 x = *(const float4*)p;
            float4 y = *(const float4*)(p + 4);
            U8 f;
            f.u[0] = pk2(x.x, x.y); f.u[1] = pk2(x.z, x.w);
            f.u[2] = pk2(y.x, y.y); f.u[3] = pk2(y.z, y.w);
            Th[kt][mt] = f.v;
        }

    short8 Ef[4];
#pragma unroll
    for (int kt = 0; kt < 4; ++kt) {
        U8 f;
        f.u[0] = pk2(ex[kt][0].x, ex[kt][0].y); f.u[1] = pk2(ex[kt][0].z, ex[kt][0].w);
        f.u[2] = pk2(ex[kt][1].x, ex[kt][1].y); f.u[3] = pk2(ex[kt][1].z, ex[kt][1].w);
        Ef[kt] = f.v;
    }

#pragma unroll
    for (int mt = 0; mt < 4; ++mt) {
        f32x4 C = {0.f, 0.f, 0.f, 0.f};
#pragma unroll
        for (int kt = 0; kt < 4; ++kt)
            C = __builtin_amdgcn_mfma_f32_16x16x32_bf16(Th[kt][mt], Ef[kt], C, 0, 0, 0);
        // C[r]: tag tt = mt*16 + q*4 + r, v-col = n
        float e[4];
#pragma unroll
        for (int r = 0; r < 4; ++r) e[r] = __expf(C[r]);
        if (valid) {
            // permuted byte position of tag tt = 32h + 8qA + j: 16*qA + 8*h + j
            // for tt = mt*16 + q*4 + r: qA=(2mt+(q>>1))&3, h=mt>>1, j=(q&1)*4+r
            int pos = 16 * ((2 * mt + (q >> 1)) & 3) + 8 * (mt >> 1) + (q & 1) * 4;
            *(unsigned*)(btn8 + (size_t)rowE * KT + pos) = pk4f8(e[0], e[1], e[2], e[3]);
        }
        // column sums: reduce over the 16 v-lanes (lane bits 0-3)
#pragma unroll
        for (int r = 0; r < 4; ++r) {
            float s = valid ? e[r] : 0.0f;
            s += __shfl_xor(s, 1, 64);
            s += __shfl_xor(s, 2, 64);
            s += __shfl_xor(s, 4, 64);
            s += __shfl_xor(s, 8, 64);
            if (n == 0) red[w][mt * 16 + q * 4 + r] = s;
        }
    }
    __syncthreads();
    if (w == 0) {
        float s = red[0][lane] + red[1][lane] + red[2][lane] + red[3][lane];
        partial[lane * PBLK + blockIdx.x] = s;
    }
}

// ---------------------------------------------------------------- sumexp[k] = sum partial[k][:]; A row k = softmax(WA row k)
__global__ __launch_bounds__(256) void k_sumA(const float* __restrict__ partial,
                                              const float* __restrict__ WA,
                                              float* __restrict__ sumexp,
                                              float* __restrict__ A) {
    __shared__ float r[4];
    int k = blockIdx.x;
    int t = threadIdx.x;
    float s = 0.0f;
    for (int i = t; i < NBLK; i += 256) s += partial[k * PBLK + i];
#pragma unroll
    for (int off = 32; off > 0; off >>= 1) s += __shfl_xor(s, off, 64);
    if ((t & 63) == 0) r[t >> 6] = s;
    __syncthreads();
    if (t == 0) sumexp[k] = r[0] + r[1] + r[2] + r[3];
    if (t < 64) {
        float wv = WA[k * KT + t];
        float e = (t == BOS_T) ? 0.0f : __expf(wv);
        float se = e;
#pragma unroll
        for (int off = 32; off > 0; off >>= 1) se += __shfl_xor(se, off, 64);
        A[k * KT + t] = e / se + EPSF;
    }
}

// ---------------------------------------------------------------- forward scan
// 512 blocks x 64 threads: one independent wave per block, 16 sentences.
// No producers, no barriers in the loop. Per-lane 16B gathers into a 9-deep
// statically-rotated register pipeline; word indices prefetched 18 ahead.
__global__ __launch_bounds__(64) void k_scan2(const int* __restrict__ words,
                                              const unsigned char* __restrict__ btn8,
                                              const float* __restrict__ A,
                                              const float* __restrict__ sumexp,
                                              float* __restrict__ out) {
    __shared__ int shw[16 * LLEN];   // 8064 B
    int lane = threadIdx.x;
    int n    = lane & 15;            // sentence col (B/C side); row m (A side)
    int qA   = lane >> 4;
    int b0   = blockIdx.x * 16;

    // Stage word indices (contiguous 8064 B = 504 uint4) with the wave.
    {
        const uint4* src = (const uint4*)(words + (size_t)b0 * LLEN);
        uint4* dst = (uint4*)shw;
#pragma unroll
        for (int it = 0; it < 8; ++it) {
            int idx = it * 64 + lane;
            if (idx < (16 * LLEN) / 4) dst[idx] = src[idx];
        }
    }

    // A-operand frags of scaled T'^T (verbatim r12); tag at C-position (mt, m):
    //   tagn = 32*(mt>>1) + 8*(m>>2) + 4*(mt&1) + (m&3)
    short8 Af[2][4];
#pragma unroll
    for (int mt = 0; mt < 4; ++mt) {
        int tagn = 32 * (mt >> 1) + 8 * (n >> 2) + 4 * (mt & 1) + (n & 3);
        float s = sumexp[tagn];
        float rsn = (tagn == BOS_T || tagn == EOS_T) ? 0.0f : (SCALE_F / s);
#pragma unroll
        for (int kt = 0; kt < 2; ++kt) {
            U8 f;
#pragma unroll
            for (int j = 0; j < 8; ++j)
                f.s[j] = f2bf(A[(kt * 32 + qA * 8 + j) * KT + tagn] * rsn);
            Af[kt][mt] = f.v;
        }
    }
    // beta_0 one-hot at tag 62 = B-position (kt=1, q=3, j=6)
    short8 B0, B1;
    {
        U8 z; z.u[0] = z.u[1] = z.u[2] = z.u[3] = 0;
        B0 = z.v;
        U8 o; o.u[0] = o.u[1] = o.u[2] = o.u[3] = 0;
        if (qA == 3) o.s[6] = (short)0x3F80;   // bf16(1.0)
        B1 = o.v;
    }
    __syncthreads();   // shw visible within the wave

    const int wrow = n * LLEN;

    // Prefetch pipeline: pf[j] holds the gather for step s (s ≡ j mod 9,
    // issued 9 steps early); wdn[j] holds the word index for step s+9.
    uint4 pf[PFD];
    int   wdn[PFD];
#pragma unroll
    for (int j = 0; j < PFD; ++j) {
        int wd = shw[wrow + j];
        pf[j] = *(const uint4*)(btn8 + (size_t)wd * KT + qA * 16);
    }
#pragma unroll
    for (int j = 0; j < PFD; ++j)
        wdn[j] = shw[wrow + PFD + j];

    for (int r = 0; r < ROUNDS; ++r) {
#pragma unroll
        for (int j = 0; j < PFD; ++j) {
            // ---- consume step s = r*PFD + j
            uint4 rc = pf[j];
            // ---- reissue: gather step s+9; refill word for step s+18
            pf[j] = *(const uint4*)(btn8 + (size_t)wdn[j] * KT + qA * 16);
            int s18 = r * PFD + j + 2 * PFD;
            s18 = s18 < LLEN ? s18 : LLEN - 1;           // clamp (tail rounds)
            wdn[j] = shw[wrow + s18];

            // decode 16 fp8 (prefetched 9 steps ago -> off the chain)
            f32x2 d0 = dec2lo(rc.x), d1 = dec2hi(rc.x);
            f32x2 d2 = dec2lo(rc.y), d3 = dec2hi(rc.y);
            f32x2 d4 = dec2lo(rc.z), d5 = dec2hi(rc.z);
            f32x2 d6 = dec2lo(rc.w), d7 = dec2hi(rc.w);

            // C[mt] = Af[0][mt] x B0 + Af[1][mt] x B1
            f32x4 C[4];
#pragma unroll
            for (int mt = 0; mt < 4; ++mt) {
                f32x4 acc = {0.f, 0.f, 0.f, 0.f};
                acc = __builtin_amdgcn_mfma_f32_16x16x32_bf16(Af[0][mt], B0, acc, 0, 0, 0);
                acc = __builtin_amdgcn_mfma_f32_16x16x32_bf16(Af[1][mt], B1, acc, 0, 0, 0);
                C[mt] = acc;
            }
            // next B-frags: kt slot j <- C[2kt+(j>>2)][j&3] * e_j  (in-lane)
            U8 f0, f1;
            f0.u[0] = pk2(C[0][0] * d0.x, C[0][1] * d0.y);
            f0.u[1] = pk2(C[0][2] * d1.x, C[0][3] * d1.y);
            f0.u[2] = pk2(C[1][0] * d2.x, C[1][1] * d2.y);
            f0.u[3] = pk2(C[1][2] * d3.x, C[1][3] * d3.y);
            f1.u[0] = pk2(C[2][0] * d4.x, C[2][1] * d4.y);
            f1.u[1] = pk2(C[2][2] * d5.x, C[2][3] * d5.y);
            f1.u[2] = pk2(C[3][0] * d6.x, C[3][1] * d6.y);
            f1.u[3] = pk2(C[3][2] * d7.x, C[3][3] * d7.y);
            B0 = f0.v; B1 = f1.v;
        }
    }

    // logZ = log(sum_k beta[k][n] * A[k][EOS]) - total scale
    {
        short8 Afin[2];
#pragma unroll
        for (int kt = 0; kt < 2; ++kt) {
            U8 f;
#pragma unroll
            for (int j = 0; j < 8; ++j)
                f.s[j] = (n == 0) ? f2bf(A[(kt * 32 + qA * 8 + j) * KT + EOS_T]) : (short)0;
            Afin[kt] = f.v;
        }
        f32x4 Cf = {0.f, 0.f, 0.f, 0.f};
        Cf = __builtin_amdgcn_mfma_f32_16x16x32_bf16(Afin[0], B0, Cf, 0, 0, 0);
        Cf = __builtin_amdgcn_mfma_f32_16x16x32_bf16(Afin[1], B1, Cf, 0, 0, 0);
        if (qA == 0)
            out[b0 + n] = logf(Cf[0]) - LOG_TOTAL_SCALE;
    }
}

extern "C" void kernel_launch(void* const* d_in, const int* in_sizes, int n_in,
                              void* d_out, int out_size, void* d_ws, size_t ws_size,
                              hipStream_t stream) {
    const int*   words  = (const int*)d_in[0];     // [8192,126]
    const float* ThetaB = (const float*)d_in[1];   // [64,128]
    const float* WA     = (const float*)d_in[2];   // [64,64]
    const float* E      = (const float*)d_in[3];   // [50000,128]
    float* out = (float*)d_out;                    // [8192]

    char* ws = (char*)d_ws;
    unsigned char* btn8 = (unsigned char*)(ws + BTN_OFF);
    float* A       = (float*)(ws + A_OFF);
    float* sumexp  = (float*)(ws + SUM_OFF);
    float* partial = (float*)(ws + PART_OFF);

    k_emit<<<NBLK, 256, 0, stream>>>(ThetaB, E, btn8, partial);
    k_sumA<<<KT, 256, 0, stream>>>(partial, WA, sumexp, A);
    k_scan2<<<8192 / 16, 64, 0, stream>>>(words, btn8, A, sumexp, out);
}

// Round 12
// 125.180 us; speedup vs baseline: 1.4471x; 1.0387x over previous
//
#include <hip/hip_runtime.h>
#include <hip/hip_bf16.h>
#include <math.h>

// HMM forward (logZ), K=64 tags, V=50000, D=128, BATCH=8192, L=126.
// r18: forward/backward SPLIT scan — halve the sequential chain.
// Evidence: three different scan structures (r12 prod/cons, r14 fused,
// r17 1-wave deep-prefetch) all leave wall at 128-130us; attribution puts
// the scan at ~40us (~760cy/step) in every variant, and all 512 scan
// waves already run concurrently -> wall == latency of ONE 126-step
// dependent chain. Only shortening the chain helps.
// Identity: logZ = log sum_s alpha_63[s]*beta_63[s]. Per block (16
// sentences, 128 threads): wave0 runs words 0..62 forward from one-hot
// BOS (verbatim r17 math); wave1 runs words 125..63 backward from
// y_T = A[:,EOS] via y <- A''(e .* y), with SCALE/S[k] folded into the
// CONTRACTED columns of the bwd A-operand (63+63 = 126 scale factors =
// same LOG_TOTAL_SCALE). The C->B in-lane renaming is reused verbatim
// (bwd B-slot tag naming k' = kt*32+qA*8+j matches the fp8 byte layout).
// Combine: both waves dump 64x16 f32 tiles to LDS, dot + 2 shfls + log.
// Chain: 126 -> 63 steps (63 = 7 rounds x 9-deep prefetch, exact).
// k_emit + k_sumA: verbatim r12 (verified).
//
// fp8 row layout: tag k = 32*h + 8*qA + j  ->  byte 16*qA + 8*h + j.
//
// ws layout (r12):
//   [0, 3,200,000)        btn8[v][64]   fp8e4m3  raw exp(logit), permuted order
//   [3,200,000, +16384)   A[i][j]       f32      softmax(WA, col BOS=-inf)+EPS
//   [3,216,384, +256)     sumexp[k]     f32
//   [3,216,640, +200704)  partial[k][784] f32    per-block column sums

#define KT 64
#define VV 50000
#define DD 128
#define BOS_T 62
#define EOS_T 63
#define LLEN 126
#define EPSF 1e-45f
#define SCALE_F 65536.0f
#define LOG_TOTAL_SCALE (2016.0f * 0.6931471805599453f)
#define NBLK 782          // k_emit grid
#define PBLK 784          // padded partial row
#define PFD 9             // prefetch depth
#define HSTEPS 63         // steps per direction (126/2)
#define HROUNDS (HSTEPS / PFD)   // 7

#define BTN_OFF   0
#define A_OFF     3200000
#define SUM_OFF   3216384
#define PART_OFF  3216640

typedef short short8 __attribute__((ext_vector_type(8)));
typedef float f32x4  __attribute__((ext_vector_type(4)));
typedef float f32x2  __attribute__((ext_vector_type(2)));

union U8 { short8 v; unsigned u[4]; short s[8]; };

static __device__ inline unsigned short f2bf_u(float x) {
    __hip_bfloat16 h = __float2bfloat16(x);
    return *reinterpret_cast<unsigned short*>(&h);
}
static __device__ inline short f2bf(float x) { return (short)f2bf_u(x); }
static __device__ inline float bf2f(short s) {
    union { unsigned u; float f; } c;
    c.u = ((unsigned)(unsigned short)s) << 16;
    return c.f;
}

#if __has_builtin(__builtin_amdgcn_cvt_pk_bf16_f32)
typedef __bf16 bf16x2 __attribute__((ext_vector_type(2)));
static __device__ inline unsigned pk2(float a, float b) {
    bf16x2 r = __builtin_amdgcn_cvt_pk_bf16_f32(a, b);
    return *reinterpret_cast<unsigned*>(&r);
}
#else
static __device__ inline unsigned pk2(float a, float b) {
    union { float f; unsigned u; } ua, ub;
    ua.f = a; ub.f = b;
    return ((ua.u + 0x8000u) >> 16) | ((ub.u + 0x8000u) & 0xFFFF0000u);
}
#endif

// ---- fp8 e4m3fn pack/unpack (values here are positive normals in [0.7,1.5])
#if __has_builtin(__builtin_amdgcn_cvt_pk_fp8_f32)
static __device__ inline unsigned pk4f8(float a, float b, float c, float d) {
    int v = __builtin_amdgcn_cvt_pk_fp8_f32(a, b, 0, false);
    v = __builtin_amdgcn_cvt_pk_fp8_f32(c, d, v, true);
    return (unsigned)v;
}
#else
static __device__ inline unsigned enc1f8(float x) {
    union { float f; unsigned u; } c; c.f = x;
    unsigned u = c.u & 0x7FFFFFFFu;
    unsigned r = u + 0x7FFFFu + ((u >> 20) & 1u);   // RNE to 3 mantissa bits
    return ((r >> 20) - (120u << 3)) & 0x7Fu;       // rebias 127->7
}
static __device__ inline unsigned pk4f8(float a, float b, float c, float d) {
    return enc1f8(a) | (enc1f8(b) << 8) | (enc1f8(c) << 16) | (enc1f8(d) << 24);
}
#endif

#if __has_builtin(__builtin_amdgcn_cvt_pk_f32_fp8)
static __device__ inline f32x2 dec2lo(unsigned w) { return __builtin_amdgcn_cvt_pk_f32_fp8((int)w, false); }
static __device__ inline f32x2 dec2hi(unsigned w) { return __builtin_amdgcn_cvt_pk_f32_fp8((int)w, true); }
#else
static __device__ inline float dec1f8(unsigned b) {
    union { unsigned u; float f; } c;
    c.u = ((b & 0x80u) << 24) | (((b & 0x7Fu) << 20) + (120u << 23));
    return c.f;
}
static __device__ inline f32x2 dec2lo(unsigned w) { f32x2 r; r.x = dec1f8(w & 0xFF); r.y = dec1f8((w >> 8) & 0xFF); return r; }
static __device__ inline f32x2 dec2hi(unsigned w) { f32x2 r; r.x = dec1f8((w >> 16) & 0xFF); r.y = dec1f8(w >> 24); return r; }
#endif

// ---------------------------------------------------------------- btn8[v][pos(k)] = fp8(exp(ThetaB[k].E[v]))  (MFMA GEMM)
__global__ __launch_bounds__(256) void k_emit(const float* __restrict__ ThetaB,
                                              const float* __restrict__ E,
                                              unsigned char* __restrict__ btn8,
                                              float* __restrict__ partial) {
    __shared__ float red[4][KT];
    int t    = threadIdx.x;
    int lane = t & 63;
    int w    = t >> 6;
    int n    = lane & 15;
    int q    = lane >> 4;
    int v0   = (blockIdx.x * 4 + w) * 16;

    int rowE = v0 + n;
    bool valid = rowE < VV;
    rowE = valid ? rowE : VV - 1;
    float4 ex[4][2];
#pragma unroll
    for (int kt = 0; kt < 4; ++kt) {
        const float* p = E + (size_t)rowE * DD + kt * 32 + q * 8;
        ex[kt][0] = *(const float4*)p;
        ex[kt][1] = *(const float4*)(p + 4);
    }

    short8 Th[4][4];
#pragma unroll
    for (int kt = 0; kt < 4; ++kt)
#pragma unroll
        for (int mt = 0; mt < 4; ++mt) {
            const float* p = ThetaB + (mt * 16 + n) * DD + kt * 32 + q * 8;
            float4 x = *(const float4*)p;
            float4 y = *(const float4*)(p + 4);
            U8 f;
            f.u[0] = pk2(x.x, x.y); f.u[1] = pk2(x.z, x.w);
            f.u[2] = pk2(y.x, y.y); f.u[3] = pk2(y.z, y.w);
            Th[kt][mt] = f.v;
        }

    short8 Ef[4];
#pragma unroll
    for (int kt = 0; kt < 4; ++kt) {
        U8 f;
        f.u[0] = pk2(ex[kt][0].x, ex[kt][0].y); f.u[1] = pk2(ex[kt][0].z, ex[kt][0].w);
        f.u[2] = pk2(ex[kt][1].x, ex[kt][1].y); f.u[3] = pk2(ex[kt][1].z, ex[kt][1].w);
        Ef[kt] = f.v;
    }

#pragma unroll
    for (int mt = 0; mt < 4; ++mt) {
        f32x4 C = {0.f, 0.f, 0.f, 0.f};
#pragma unroll
        for (int kt = 0; kt < 4; ++kt)
            C = __builtin_amdgcn_mfma_f32_16x16x32_bf16(Th[kt][mt], Ef[kt], C, 0, 0, 0);
        float e[4];
#pragma unroll
        for (int r = 0; r < 4; ++r) e[r] = __expf(C[r]);
        if (valid) {
            // tag tt = mt*16 + q*4 + r -> byte 16*qA + 8*h + j
            int pos = 16 * ((2 * mt + (q >> 1)) & 3) + 8 * (mt >> 1) + (q & 1) * 4;
            *(unsigned*)(btn8 + (size_t)rowE * KT + pos) = pk4f8(e[0], e[1], e[2], e[3]);
        }
#pragma unroll
        for (int r = 0; r < 4; ++r) {
            float s = valid ? e[r] : 0.0f;
            s += __shfl_xor(s, 1, 64);
            s += __shfl_xor(s, 2, 64);
            s += __shfl_xor(s, 4, 64);
            s += __shfl_xor(s, 8, 64);
            if (n == 0) red[w][mt * 16 + q * 4 + r] = s;
        }
    }
    __syncthreads();
    if (w == 0) {
        float s = red[0][lane] + red[1][lane] + red[2][lane] + red[3][lane];
        partial[lane * PBLK + blockIdx.x] = s;
    }
}

// ---------------------------------------------------------------- sumexp[k] = sum partial[k][:]; A row k = softmax(WA row k)
__global__ __launch_bounds__(256) void k_sumA(const float* __restrict__ partial,
                                              const float* __restrict__ WA,
                                              float* __restrict__ sumexp,
                                              float* __restrict__ A) {
    __shared__ float r[4];
    int k = blockIdx.x;
    int t = threadIdx.x;
    float s = 0.0f;
    for (int i = t; i < NBLK; i += 256) s += partial[k * PBLK + i];
#pragma unroll
    for (int off = 32; off > 0; off >>= 1) s += __shfl_xor(s, off, 64);
    if ((t & 63) == 0) r[t >> 6] = s;
    __syncthreads();
    if (t == 0) sumexp[k] = r[0] + r[1] + r[2] + r[3];
    if (t < 64) {
        float wv = WA[k * KT + t];
        float e = (t == BOS_T) ? 0.0f : __expf(wv);
        float se = e;
#pragma unroll
        for (int off = 32; off > 0; off >>= 1) se += __shfl_xor(se, off, 64);
        A[k * KT + t] = e / se + EPSF;
    }
}

// ---------------------------------------------------------------- split scan
// 512 blocks x 128 threads (2 waves), 16 sentences per block.
// wave0: alpha_63 forward (words 0..62, verbatim r17 chain).
// wave1: beta_63 backward (words 125..63), y <- A''(e .* y) from A[:,EOS].
// Combine: logZ = log(sum_tag x*y) - LOG_TOTAL_SCALE.
__global__ __launch_bounds__(128) void k_scan3(const int* __restrict__ words,
                                               const unsigned char* __restrict__ btn8,
                                               const float* __restrict__ A,
                                               const float* __restrict__ sumexp,
                                               float* __restrict__ out) {
    __shared__ int shw[16 * LLEN];    // 8064 B
    __shared__ float scl[KT];         // 256 B
    __shared__ float ldx[KT][16];     // 4096 B  alpha_63 (tag, sentence)
    __shared__ float ldy[KT][16];     // 4096 B  beta_63
    int t    = threadIdx.x;
    int lane = t & 63;
    int w    = t >> 6;                // 0 = forward, 1 = backward
    int n    = lane & 15;
    int qA   = lane >> 4;
    int b0   = blockIdx.x * 16;

    // stage word indices (both waves cooperate)
    {
        const uint4* src = (const uint4*)(words + (size_t)b0 * LLEN);
        uint4* dst = (uint4*)shw;
        for (int idx = t; idx < (16 * LLEN) / 4; idx += 128)
            dst[idx] = src[idx];
    }
    // contracted-tag scale table for the backward A-operand
    if (t < KT)
        scl[t] = (t == BOS_T || t == EOS_T) ? 0.0f : (SCALE_F / sumexp[t]);
    __syncthreads();

    const int wrow = n * LLEN;

    if (w == 0) {
        // ================= forward: words 0..62 from one-hot BOS =================
        short8 Af[2][4];
#pragma unroll
        for (int mt = 0; mt < 4; ++mt) {
            int tagn = 32 * (mt >> 1) + 8 * (n >> 2) + 4 * (mt & 1) + (n & 3);
            float s = sumexp[tagn];
            float rsn = (tagn == BOS_T || tagn == EOS_T) ? 0.0f : (SCALE_F / s);
#pragma unroll
            for (int kt = 0; kt < 2; ++kt) {
                U8 f;
#pragma unroll
                for (int j = 0; j < 8; ++j)
                    f.s[j] = f2bf(A[(kt * 32 + qA * 8 + j) * KT + tagn] * rsn);
                Af[kt][mt] = f.v;
            }
        }
        short8 B0, B1;
        {
            U8 z; z.u[0] = z.u[1] = z.u[2] = z.u[3] = 0;
            B0 = z.v;
            U8 o; o.u[0] = o.u[1] = o.u[2] = o.u[3] = 0;
            if (qA == 3) o.s[6] = (short)0x3F80;   // bf16(1.0) at tag 62 = BOS
            B1 = o.v;
        }

        uint4 pf[PFD];
        int   wdn[PFD];
#pragma unroll
        for (int j = 0; j < PFD; ++j) {
            int wd = shw[wrow + j];
            pf[j] = *(const uint4*)(btn8 + (size_t)wd * KT + qA * 16);
        }
#pragma unroll
        for (int j = 0; j < PFD; ++j)
            wdn[j] = shw[wrow + PFD + j];

        for (int r = 0; r < HROUNDS; ++r) {
#pragma unroll
            for (int j = 0; j < PFD; ++j) {
                uint4 rc = pf[j];
                pf[j] = *(const uint4*)(btn8 + (size_t)wdn[j] * KT + qA * 16);
                int s18 = r * PFD + j + 2 * PFD;
                s18 = s18 < HSTEPS ? s18 : HSTEPS - 1;
                wdn[j] = shw[wrow + s18];

                f32x2 d0 = dec2lo(rc.x), d1 = dec2hi(rc.x);
                f32x2 d2 = dec2lo(rc.y), d3 = dec2hi(rc.y);
                f32x2 d4 = dec2lo(rc.z), d5 = dec2hi(rc.z);
                f32x2 d6 = dec2lo(rc.w), d7 = dec2hi(rc.w);

                f32x4 C[4];
#pragma unroll
                for (int mt = 0; mt < 4; ++mt) {
                    f32x4 acc = {0.f, 0.f, 0.f, 0.f};
                    acc = __builtin_amdgcn_mfma_f32_16x16x32_bf16(Af[0][mt], B0, acc, 0, 0, 0);
                    acc = __builtin_amdgcn_mfma_f32_16x16x32_bf16(Af[1][mt], B1, acc, 0, 0, 0);
                    C[mt] = acc;
                }
                U8 f0, f1;
                f0.u[0] = pk2(C[0][0] * d0.x, C[0][1] * d0.y);
                f0.u[1] = pk2(C[0][2] * d1.x, C[0][3] * d1.y);
                f0.u[2] = pk2(C[1][0] * d2.x, C[1][1] * d2.y);
                f0.u[3] = pk2(C[1][2] * d3.x, C[1][3] * d3.y);
                f1.u[0] = pk2(C[2][0] * d4.x, C[2][1] * d4.y);
                f1.u[1] = pk2(C[2][2] * d5.x, C[2][3] * d5.y);
                f1.u[2] = pk2(C[3][0] * d6.x, C[3][1] * d6.y);
                f1.u[3] = pk2(C[3][2] * d7.x, C[3][3] * d7.y);
                B0 = f0.v; B1 = f1.v;
            }
        }
        // x63 -> LDS: B-slot tag = kt*32 + qA*8 + j
        U8 bx0, bx1; bx0.v = B0; bx1.v = B1;
#pragma unroll
        for (int j = 0; j < 8; ++j) {
            ldx[qA * 8 + j][n]      = bf2f(bx0.s[j]);
            ldx[32 + qA * 8 + j][n] = bf2f(bx1.s[j]);
        }
    } else {
        // ================= backward: words 125..63 from y_T = A[:,EOS] ==========
        // Aop_bwd[s-row, k'] = A[tagn(s), k'] * scl[k']  (scale on contracted idx)
        short8 Af[2][4];
#pragma unroll
        for (int mt = 0; mt < 4; ++mt) {
            int tagn = 32 * (mt >> 1) + 8 * (n >> 2) + 4 * (mt & 1) + (n & 3);
#pragma unroll
            for (int kt = 0; kt < 2; ++kt) {
                U8 f;
#pragma unroll
                for (int j = 0; j < 8; ++j) {
                    int kc = kt * 32 + qA * 8 + j;
                    f.s[j] = f2bf(A[tagn * KT + kc] * scl[kc]);
                }
                Af[kt][mt] = f.v;
            }
        }
        // y_T in C-layout: C[mt][r] at (n, qA) = A[tag(mt,qA,r), EOS]
        f32x4 C[4];
#pragma unroll
        for (int mt = 0; mt < 4; ++mt)
#pragma unroll
            for (int r = 0; r < 4; ++r) {
                int tg = 32 * (mt >> 1) + 8 * qA + 4 * (mt & 1) + r;
                C[mt][r] = A[tg * KT + EOS_T];
            }

        uint4 pf[PFD];
        int   wdn[PFD];
#pragma unroll
        for (int j = 0; j < PFD; ++j) {
            int wd = shw[wrow + (LLEN - 1 - j)];
            pf[j] = *(const uint4*)(btn8 + (size_t)wd * KT + qA * 16);
        }
#pragma unroll
        for (int j = 0; j < PFD; ++j)
            wdn[j] = shw[wrow + (LLEN - 1 - (PFD + j))];

        for (int r = 0; r < HROUNDS; ++r) {
#pragma unroll
            for (int j = 0; j < PFD; ++j) {
                uint4 rc = pf[j];
                pf[j] = *(const uint4*)(btn8 + (size_t)wdn[j] * KT + qA * 16);
                int itn = r * PFD + j + 2 * PFD;
                itn = itn < HSTEPS ? itn : HSTEPS - 1;
                wdn[j] = shw[wrow + (LLEN - 1 - itn)];

                f32x2 d0 = dec2lo(rc.x), d1 = dec2hi(rc.x);
                f32x2 d2 = dec2lo(rc.y), d3 = dec2hi(rc.y);
                f32x2 d4 = dec2lo(rc.z), d5 = dec2hi(rc.z);
                f32x2 d6 = dec2lo(rc.w), d7 = dec2hi(rc.w);

                // B = pk2(C .* e)  (elementwise BEFORE matvec in bwd)
                U8 f0, f1;
                f0.u[0] = pk2(C[0][0] * d0.x, C[0][1] * d0.y);
                f0.u[1] = pk2(C[0][2] * d1.x, C[0][3] * d1.y);
                f0.u[2] = pk2(C[1][0] * d2.x, C[1][1] * d2.y);
                f0.u[3] = pk2(C[1][2] * d3.x, C[1][3] * d3.y);
                f1.u[0] = pk2(C[2][0] * d4.x, C[2][1] * d4.y);
                f1.u[1] = pk2(C[2][2] * d5.x, C[2][3] * d5.y);
                f1.u[2] = pk2(C[3][0] * d6.x, C[3][1] * d6.y);
                f1.u[3] = pk2(C[3][2] * d7.x, C[3][3] * d7.y);
                short8 B0 = f0.v, B1 = f1.v;

#pragma unroll
                for (int mt = 0; mt < 4; ++mt) {
                    f32x4 acc = {0.f, 0.f, 0.f, 0.f};
                    acc = __builtin_amdgcn_mfma_f32_16x16x32_bf16(Af[0][mt], B0, acc, 0, 0, 0);
                    acc = __builtin_amdgcn_mfma_f32_16x16x32_bf16(Af[1][mt], B1, acc, 0, 0, 0);
                    C[mt] = acc;
                }
            }
        }
        // y63 -> LDS: C-position tag = 32*(mt>>1) + 8*qA + 4*(mt&1) + r
#pragma unroll
        for (int mt = 0; mt < 4; ++mt)
#pragma unroll
            for (int r = 0; r < 4; ++r) {
                int tg = 32 * (mt >> 1) + 8 * qA + 4 * (mt & 1) + r;
                ldy[tg][n] = C[mt][r];
            }
    }
    __syncthreads();

    // combine: logZ[n] = log(sum_tag x*y) - LOG_TOTAL_SCALE  (wave 0)
    if (w == 0) {
        float s = 0.0f;
#pragma unroll
        for (int kk = 0; kk < 16; ++kk) {
            int tg = qA * 16 + kk;
            s += ldx[tg][n] * ldy[tg][n];
        }
        s += __shfl_xor(s, 16, 64);
        s += __shfl_xor(s, 32, 64);
        if (qA == 0)
            out[b0 + n] = logf(s) - LOG_TOTAL_SCALE;
    }
}

extern "C" void kernel_launch(void* const* d_in, const int* in_sizes, int n_in,
                              void* d_out, int out_size, void* d_ws, size_t ws_size,
                              hipStream_t stream) {
    const int*   words  = (const int*)d_in[0];     // [8192,126]
    const float* ThetaB = (const float*)d_in[1];   // [64,128]
    const float* WA     = (const float*)d_in[2];   // [64,64]
    const float* E      = (const float*)d_in[3];   // [50000,128]
    float* out = (float*)d_out;                    // [8192]

    char* ws = (char*)d_ws;
    unsigned char* btn8 = (unsigned char*)(ws + BTN_OFF);
    float* A       = (float*)(ws + A_OFF);
    float* sumexp  = (float*)(ws + SUM_OFF);
    float* partial = (float*)(ws + PART_OFF);

    k_emit<<<NBLK, 256, 0, stream>>>(ThetaB, E, btn8, partial);
    k_sumA<<<KT, 256, 0, stream>>>(partial, WA, sumexp, A);
    k_scan3<<<8192 / 16, 128, 0, stream>>>(words, btn8, A, sumexp, out);
}